// Round 12
// baseline (240.563 us; speedup 1.0000x reference)
//
#include <hip/hip_runtime.h>
#include <hip/hip_bf16.h>

// Problem constants
#define BATCH  16384
#define DIM    512
#define NLAYER 3
#define NEXP   4
#define RANK   128

typedef __bf16 bf16_t;
typedef bf16_t bf16x8 __attribute__((ext_vector_type(8)));
typedef bf16_t bf16x4 __attribute__((ext_vector_type(4)));
typedef float  f32x4  __attribute__((ext_vector_type(4)));

__device__ __forceinline__ float tanh_fast(float x) {
    float e = __expf(2.0f * x);
    return 1.0f - 2.0f * __builtin_amdgcn_rcpf(e + 1.0f);
}
// XOR-swizzle 16B slots by row (bits 4..6): A-frag reads 2-way max (free)
__device__ __forceinline__ int swz(int row, int b) { return b ^ ((row & 7) << 4); }

__device__ __forceinline__ bf16x8 ldsr(const bf16_t* base, int row, int kb) {
    return *(const bf16x8*)((const char*)base + row * 1024 + swz(row, kb));
}
__device__ __forceinline__ void ldsw2(bf16_t* base, int row, int cb, bf16_t v) {
    *(bf16_t*)((char*)base + row * 1024 + swz(row, cb)) = v;
}
// LDS-only barrier: drain ds ops, do NOT drain vmcnt.
__device__ __forceinline__ void barrier_lds() {
    asm volatile("s_waitcnt lgkmcnt(0)" ::: "memory");
    __builtin_amdgcn_s_barrier();
}
// AGPR stash: residual state lives in accumulator registers, outside the
// allocator's 128-arch-VGPR heuristic cap. Only touched at layer bounds.
__device__ __forceinline__ void ag_w(float& a, float v) {
    asm volatile("v_accvgpr_write_b32 %0, %1" : "=a"(a) : "v"(v));
}
__device__ __forceinline__ float ag_r(float a) {
    float v;
    asm volatile("v_accvgpr_read_b32 %0, %1" : "=v"(v) : "a"(a));
    return v;
}

// ---- prep: pack weights into per-wave MFMA fragment stream order ----
// 8 waves; wave wn owns output cols [wn*64, wn*64+64) (ni = 0..3).
// Every in-kernel weight load is base + lane*16B, sequential walk.
__global__ void prep_pack(const float* __restrict__ Vs,
                          const float* __restrict__ Us,
                          const float* __restrict__ Cs,
                          bf16_t* __restrict__ Vp,
                          bf16_t* __restrict__ Up,
                          bf16_t* __restrict__ Cp) {
    int t = blockIdx.x * 256 + threadIdx.x;
    if (t < 98304) {                       // V: XV = xl @ Vcat (N=512,K=512)
        int lane = t & 63, ni = (t >> 6) & 3, ks = (t >> 8) & 15,
            wn = (t >> 12) & 7, l = t >> 15;
        int c = wn * 64 + ni * 16 + (lane & 15), e = c >> 7, r = c & 127;
        int d0 = ks * 32 + (lane >> 4) * 8;
        const float* src = Vs + ((size_t)(l * NEXP + e) * DIM + d0) * RANK + r;
        bf16x8 v;
        #pragma unroll
        for (int j = 0; j < 8; ++j) v[j] = (bf16_t)src[j * RANK];
        *(bf16x8*)(Vp + (size_t)t * 8) = v;
    } else if (t < 196608) {               // U: XU = XC @ Ucat^T (N=512,K=512)
        int q = t - 98304;
        int lane = q & 63, ni = (q >> 6) & 3, ks = (q >> 8) & 15,
            wn = (q >> 12) & 7, l = q >> 15;
        int d = wn * 64 + ni * 16 + (lane & 15);
        int k0 = ks * 32 + (lane >> 4) * 8, e = k0 >> 7, r0 = k0 & 127;
        const float* src = Us + ((size_t)(l * NEXP + e) * DIM + d) * RANK + r0;
        bf16x8 v;
        #pragma unroll
        for (int j = 0; j < 8; ++j) v[j] = (bf16_t)src[j];
        *(bf16x8*)(Up + (size_t)q * 8) = v;
    } else if (t < 221184) {               // C: XC = XV @ C^T (block-diag K)
        int q = t - 196608;
        int lane = q & 63, ni = (q >> 6) & 3, k4 = (q >> 8) & 3,
            wn = (q >> 10) & 7, l = q >> 13;
        int e = wn >> 1, rp = (wn & 1) * 64 + ni * 16 + (lane & 15);
        int s0 = k4 * 32 + (lane >> 4) * 8;
        const float* src = Cs + ((size_t)(l * NEXP + e) * RANK + rp) * RANK + s0;
        bf16x8 v;
        #pragma unroll
        for (int j = 0; j < 8; ++j) v[j] = (bf16_t)src[j];
        *(bf16x8*)(Cp + (size_t)q * 8) = v;
    }
}

// ---------------- fused 3-layer kernel ----------------
// 256 blocks x 64 rows x 512 threads (8 waves, 64-col N-slices).
// M=64 halves the L2 weight stream vs M=32 (256 blocks x 3.4MB = 880MB).
// Residual f32 (64 vals/thread) stashed in AGPRs via v_accvgpr asm ->
// hot-loop arch pressure ~100 <= the 128 cap, no scratch spills.
// Ping-pong 2x64KB LDS, 3 lgkm-only barriers/layer.

__global__ __launch_bounds__(512)
void fused3(const float* __restrict__ x,     // (B, 512) f32 (= x0)
            const bf16_t* __restrict__ Vp,
            const bf16_t* __restrict__ Up,
            const bf16_t* __restrict__ Cp,
            const float* __restrict__ bb,    // [L][D]
            float* __restrict__ out)         // (B, 512) f32
{
    __shared__ __align__(16) char smem[131072];
    bf16_t* bufA = (bf16_t*)smem;            // 64 rows x 1024 B, swizzled
    bf16_t* bufB = (bf16_t*)(smem + 65536);

    const int tid  = threadIdx.x;
    const int lane = tid & 63;
    const int wn   = tid >> 6;       // 0..7: wave's 64-col slice
    const int lr   = lane & 15;
    const int lg   = lane >> 4;
    const int m0   = blockIdx.x * 64;

    // ---- init: bufA = bf16(x stripe) ----
    #pragma unroll
    for (int it = 0; it < 16; ++it) {
        int q = tid + 512 * it;                      // 8192 float4 groups
        int row = q >> 7, c4 = (q & 127) << 2;
        float4 v = *(const float4*)(x + (size_t)(m0 + row) * DIM + c4);
        bf16x4 b4 = { (bf16_t)v.x, (bf16_t)v.y, (bf16_t)v.z, (bf16_t)v.w };
        *(bf16x4*)((char*)bufA + row * 1024 + swz(row, c4 * 2)) = b4;
    }
    // residual: f32 in AGPR stash; x0 as bf16 in VGPRs
    float   xs[4][4][4];                 // AGPR-tied (static indices only)
    bf16x4  x0r[4][4];
    #pragma unroll
    for (int mi = 0; mi < 4; ++mi)
        #pragma unroll
        for (int ni = 0; ni < 4; ++ni)
            #pragma unroll
            for (int j = 0; j < 4; ++j) {
                int row = mi * 16 + lg * 4 + j, col = wn * 64 + ni * 16 + lr;
                float v = x[(size_t)(m0 + row) * DIM + col];
                ag_w(xs[mi][ni][j], v);
                x0r[mi][ni][j] = (bf16_t)v;
            }
    barrier_lds();

    #pragma unroll 1
    for (int l = 0; l < NLAYER; ++l) {
        bf16_t* xl_b = (l & 1) ? bufB : bufA;    // holds xl at layer entry
        bf16_t* xv_b = (l & 1) ? bufA : bufB;    // gets XV, then new xl

        const bf16_t* Vw = Vp + (((size_t)l * 8 + wn) << 15) + lane * 8;
        const bf16_t* Uw = Up + (((size_t)l * 8 + wn) << 15) + lane * 8;
        const bf16_t* Cw = Cp + (((size_t)l * 8 + wn) << 13) + lane * 8;

        // ---- ph1: XV = xl @ Vcat  (64 x 64-per-wave, K=512) ----
        {
            f32x4 a1[4][4] = {};
            const bf16_t* vp = Vw;                   // sequential frag walk
            #pragma unroll 2
            for (int ks = 0; ks < 16; ++ks) {
                bf16x8 bv[4];
                #pragma unroll
                for (int ni = 0; ni < 4; ++ni)
                    bv[ni] = *(const bf16x8*)(vp + ni * 512);
                vp += 2048;
                #pragma unroll
                for (int mi = 0; mi < 4; ++mi) {
                    bf16x8 av = ldsr(xl_b, mi * 16 + lr, ks * 64 + lg * 16);
                    #pragma unroll
                    for (int ni = 0; ni < 4; ++ni)
                        a1[mi][ni] = __builtin_amdgcn_mfma_f32_16x16x32_bf16(
                            av, bv[ni], a1[mi][ni], 0, 0, 0);
                }
            }
            // tanh -> XV into xv_b (fresh buffer)
            #pragma unroll
            for (int mi = 0; mi < 4; ++mi)
                #pragma unroll
                for (int ni = 0; ni < 4; ++ni)
                    #pragma unroll
                    for (int j = 0; j < 4; ++j)
                        ldsw2(xv_b, mi * 16 + lg * 4 + j,
                              (wn * 64 + ni * 16 + lr) * 2,
                              (bf16_t)tanh_fast(a1[mi][ni][j]));
            barrier_lds();                           // B_XV: XV visible
        }

        // ---- ph2: XC = XV @ C^T (block-diag; wave's K = own expert) ----
        {
            const int eb = (wn >> 1) * 256;          // expert K-base, bytes
            f32x4 a2[4][4] = {};
            #pragma unroll 2
            for (int k4 = 0; k4 < 4; ++k4) {
                bf16x8 bv[4];
                #pragma unroll
                for (int ni = 0; ni < 4; ++ni)
                    bv[ni] = *(const bf16x8*)(Cw + (k4 * 4 + ni) * 512);
                #pragma unroll
                for (int mi = 0; mi < 4; ++mi) {
                    bf16x8 av = ldsr(xv_b, mi * 16 + lr, eb + k4 * 64 + lg * 16);
                    #pragma unroll
                    for (int ni = 0; ni < 4; ++ni)
                        a2[mi][ni] = __builtin_amdgcn_mfma_f32_16x16x32_bf16(
                            av, bv[ni], a2[mi][ni], 0, 0, 0);
                }
            }
            // tanh -> XC into xl_b (xl dead after ph1; all waves past B_XV)
            #pragma unroll
            for (int mi = 0; mi < 4; ++mi)
                #pragma unroll
                for (int ni = 0; ni < 4; ++ni)
                    #pragma unroll
                    for (int j = 0; j < 4; ++j)
                        ldsw2(xl_b, mi * 16 + lg * 4 + j,
                              (wn * 64 + ni * 16 + lr) * 2,
                              (bf16_t)tanh_fast(a2[mi][ni][j]));
            barrier_lds();                           // B_XC: XC visible
        }

        // ---- ph3: xu = XC @ Ucat^T  (64 x 64-per-wave, K=512 concat) ----
        {
            f32x4 a3[4][4] = {};
            const bf16_t* up = Uw;
            #pragma unroll 2
            for (int ks = 0; ks < 16; ++ks) {
                bf16x8 bv[4];
                #pragma unroll
                for (int ni = 0; ni < 4; ++ni)
                    bv[ni] = *(const bf16x8*)(up + ni * 512);
                up += 2048;
                #pragma unroll
                for (int mi = 0; mi < 4; ++mi) {
                    bf16x8 av = ldsr(xl_b, mi * 16 + lr, ks * 64 + lg * 16);
                    #pragma unroll
                    for (int ni = 0; ni < 4; ++ni)
                        a3[mi][ni] = __builtin_amdgcn_mfma_f32_16x16x32_bf16(
                            av, bv[ni], a3[mi][ni], 0, 0, 0);
                }
            }

            // ---- residual: xl += x0 * (xu + E*bias); unstash/restash ----
            const float* bl = bb + l * DIM;
            const bool last = (l == NLAYER - 1);
            #pragma unroll
            for (int ni = 0; ni < 4; ++ni) {
                int col = wn * 64 + ni * 16 + lr;
                float b4v = 4.0f * bl[col];
                #pragma unroll
                for (int mi = 0; mi < 4; ++mi)
                    #pragma unroll
                    for (int j = 0; j < 4; ++j) {
                        float v = ag_r(xs[mi][ni][j]) +
                                  (float)x0r[mi][ni][j] * (a3[mi][ni][j] + b4v);
                        if (last) {
                            int row = mi * 16 + lg * 4 + j;
                            out[(size_t)(m0 + row) * DIM + col] = v;
                        } else {
                            ag_w(xs[mi][ni][j], v);
                            ldsw2(xv_b, mi * 16 + lg * 4 + j, col * 2, (bf16_t)v);
                        }
                    }
            }
        }

        if (l < NLAYER - 1)
            barrier_lds();                           // B_xl: new xl visible
    }
}

// ---------------- host ----------------

extern "C" void kernel_launch(void* const* d_in, const int* in_sizes, int n_in,
                              void* d_out, int out_size, void* d_ws, size_t ws_size,
                              hipStream_t stream) {
    const float* x  = (const float*)d_in[0];   // (B, D)
    const float* Us = (const float*)d_in[1];   // (L, E, D, R)
    const float* Cs = (const float*)d_in[2];   // (L, E, R, R)
    const float* Vs = (const float*)d_in[3];   // (L, E, D, R)
    // d_in[4] = G: softmax over singleton axis == 1.0 -> unused
    const float* bb = (const float*)d_in[5];   // (L, D)
    float* out = (float*)d_out;

    bf16_t* Vp = (bf16_t*)d_ws;                // 786432 bf16
    bf16_t* Up = Vp + 786432;                  // 786432 bf16
    bf16_t* Cp = Up + 786432;                  // 196608 bf16

    prep_pack<<<864, 256, 0, stream>>>(Vs, Us, Cs, Vp, Up, Cp);
    fused3<<<BATCH / 64, 512, 0, stream>>>(x, Vp, Up, Cp, bb, out);
}

// Round 13
// 132.484 us; speedup vs baseline: 1.8158x; 1.8158x over previous
//
#include <hip/hip_runtime.h>
#include <hip/hip_bf16.h>

// Problem constants
#define BATCH  16384
#define DIM    512
#define NLAYER 3
#define NEXP   4
#define RANK   128

typedef __bf16 bf16_t;
typedef bf16_t bf16x8 __attribute__((ext_vector_type(8)));
typedef bf16_t bf16x4 __attribute__((ext_vector_type(4)));
typedef float  f32x4  __attribute__((ext_vector_type(4)));

__device__ __forceinline__ float tanh_fast(float x) {
    float e = __expf(2.0f * x);
    return 1.0f - 2.0f * __builtin_amdgcn_rcpf(e + 1.0f);
}
// XOR-swizzle 16B slots by row (bits 4..6): A-frag reads 2-way max (free)
__device__ __forceinline__ int swz(int row, int b) { return b ^ ((row & 7) << 4); }

__device__ __forceinline__ bf16x8 ldsr(const bf16_t* base, int row, int kb) {
    return *(const bf16x8*)((const char*)base + row * 1024 + swz(row, kb));
}
__device__ __forceinline__ void ldsw2(bf16_t* base, int row, int cb, bf16_t v) {
    *(bf16_t*)((char*)base + row * 1024 + swz(row, cb)) = v;
}
// LDS-only barrier: drain ds ops, do NOT drain vmcnt.
__device__ __forceinline__ void barrier_lds() {
    asm volatile("s_waitcnt lgkmcnt(0)" ::: "memory");
    __builtin_amdgcn_s_barrier();
}

// ---- prep: pack weights into per-wave MFMA fragment stream order ----
// 16 waves/block; wave wn owns output cols [wn*32, wn*32+32) (ni = 0..1).
// Every in-kernel weight load is base + lane*16B, sequential walk.
__global__ void prep_pack(const float* __restrict__ Vs,
                          const float* __restrict__ Us,
                          const float* __restrict__ Cs,
                          bf16_t* __restrict__ Vp,
                          bf16_t* __restrict__ Up,
                          bf16_t* __restrict__ Cp) {
    int t = blockIdx.x * 256 + threadIdx.x;
    if (t < 98304) {                 // V: XV = xl @ Vcat (N=512, K=512)
        int lane = t & 63, ni = (t >> 6) & 1, ks = (t >> 7) & 15,
            wn = (t >> 11) & 15, l = t >> 15;
        int c = wn * 32 + ni * 16 + (lane & 15), e = c >> 7, r = c & 127;
        int d0 = ks * 32 + (lane >> 4) * 8;
        const float* src = Vs + ((size_t)(l * NEXP + e) * DIM + d0) * RANK + r;
        bf16x8 v;
        #pragma unroll
        for (int j = 0; j < 8; ++j) v[j] = (bf16_t)src[j * RANK];
        *(bf16x8*)(Vp + (size_t)t * 8) = v;
    } else if (t < 196608) {         // U: XU = XC @ Ucat^T (N=512, K=512)
        int q = t - 98304;
        int lane = q & 63, ni = (q >> 6) & 1, ks = (q >> 7) & 15,
            wn = (q >> 11) & 15, l = q >> 15;
        int d = wn * 32 + ni * 16 + (lane & 15);
        int k0 = ks * 32 + (lane >> 4) * 8, e = k0 >> 7, r0 = k0 & 127;
        const float* src = Us + ((size_t)(l * NEXP + e) * DIM + d) * RANK + r0;
        bf16x8 v;
        #pragma unroll
        for (int j = 0; j < 8; ++j) v[j] = (bf16_t)src[j];
        *(bf16x8*)(Up + (size_t)q * 8) = v;
    } else if (t < 221184) {         // C: XC = XV @ C^T (block-diag K)
        int q = t - 196608;
        int lane = q & 63, ni = (q >> 6) & 1, k4 = (q >> 7) & 3,
            wn = (q >> 9) & 15, l = q >> 13;
        int c = wn * 32 + ni * 16 + (lane & 15);   // global R-col
        int e = wn >> 2, rp = c & 127;             // expert, row within expert
        int s0 = k4 * 32 + (lane >> 4) * 8;
        const float* src = Cs + ((size_t)(l * NEXP + e) * RANK + rp) * RANK + s0;
        bf16x8 v;
        #pragma unroll
        for (int j = 0; j < 8; ++j) v[j] = (bf16_t)src[j];
        *(bf16x8*)(Cp + (size_t)q * 8) = v;
    }
}

// ---------------- per-layer kernel ----------------
// 256 blocks x 64 rows x 1024 threads (16 waves, each a 32-col N-slice).
// NO persistent residual state: f32 residual lives in global (in-place on
// xl_out; all accesses row-local per block -> no races, L3-resident).
// Hot-loop regs: acc[4][2]=32 + windows ~28 fits the 64-VGPR cap at 1024thr
// (R10/R11's spills were the now-deleted 130-reg persistent state).
// Weight L2 stream: 256 blocks x 1.15MB/layer = 295MB/layer.
// Ping-pong 2x64KB LDS: xl->A, XV->B, XC->A. 3 lgkm-only barriers.

__global__ __launch_bounds__(1024)
void k_layer(const float* xl_in,              // f32 (B,512) layer input
             const float* __restrict__ x0,    // f32 (B,512) original x
             const bf16_t* __restrict__ Vw0,  // this layer's packed V
             const bf16_t* __restrict__ Uw0,
             const bf16_t* __restrict__ Cw0,
             const float* __restrict__ bl,    // this layer's bias (D)
             float* xl_out)                   // f32 (B,512); may == xl_in
{
    __shared__ __align__(16) char smem[131072];
    bf16_t* bufA = (bf16_t*)smem;            // 64 rows x 1024 B, swizzled
    bf16_t* bufB = (bf16_t*)(smem + 65536);

    const int tid  = threadIdx.x;
    const int lane = tid & 63;
    const int wn   = tid >> 6;       // 0..15: wave's 32-col slice
    const int lr   = lane & 15;
    const int lg   = lane >> 4;
    const int m0   = blockIdx.x * 64;

    // ---- stage xl (f32 global -> bf16 LDS, swizzled) ----
    #pragma unroll
    for (int it = 0; it < 8; ++it) {
        int q = tid + 1024 * it;                     // 8192 float4 groups
        int row = q >> 7, c4 = (q & 127) << 2;
        float4 v = *(const float4*)(xl_in + (size_t)(m0 + row) * DIM + c4);
        bf16x4 b4 = { (bf16_t)v.x, (bf16_t)v.y, (bf16_t)v.z, (bf16_t)v.w };
        *(bf16x4*)((char*)bufA + row * 1024 + swz(row, c4 * 2)) = b4;
    }
    barrier_lds();

    const bf16_t* Vw = Vw0 + ((size_t)wn << 14) + lane * 8;
    const bf16_t* Uw = Uw0 + ((size_t)wn << 14) + lane * 8;
    const bf16_t* Cw = Cw0 + ((size_t)wn << 12) + lane * 8;

    // ---- ph1: XV = xl @ Vcat  (64 x 32-per-wave, K=512) ----
    {
        f32x4 a1[4][2] = {};
        const bf16_t* vp = Vw;                       // sequential frag walk
        #pragma unroll 2
        for (int ks = 0; ks < 16; ++ks) {
            bf16x8 bv0 = *(const bf16x8*)(vp);
            bf16x8 bv1 = *(const bf16x8*)(vp + 512);
            vp += 1024;
            #pragma unroll
            for (int mi = 0; mi < 4; ++mi) {
                bf16x8 av = ldsr(bufA, mi * 16 + lr, ks * 64 + lg * 16);
                a1[mi][0] = __builtin_amdgcn_mfma_f32_16x16x32_bf16(
                    av, bv0, a1[mi][0], 0, 0, 0);
                a1[mi][1] = __builtin_amdgcn_mfma_f32_16x16x32_bf16(
                    av, bv1, a1[mi][1], 0, 0, 0);
            }
        }
        // tanh -> XV into bufB (fresh buffer)
        #pragma unroll
        for (int mi = 0; mi < 4; ++mi)
            #pragma unroll
            for (int ni = 0; ni < 2; ++ni)
                #pragma unroll
                for (int j = 0; j < 4; ++j)
                    ldsw2(bufB, mi * 16 + lg * 4 + j,
                          (wn * 32 + ni * 16 + lr) * 2,
                          (bf16_t)tanh_fast(a1[mi][ni][j]));
        barrier_lds();                               // B_XV: XV visible
    }

    // ---- ph2: XC = XV @ C^T (block-diag; wave's K = own expert) ----
    {
        const int eb = (wn >> 2) * 256;              // expert K-base, bytes
        f32x4 a2[4][2] = {};
        #pragma unroll 2
        for (int k4 = 0; k4 < 4; ++k4) {
            bf16x8 bv0 = *(const bf16x8*)(Cw + (k4 * 2 + 0) * 512);
            bf16x8 bv1 = *(const bf16x8*)(Cw + (k4 * 2 + 1) * 512);
            #pragma unroll
            for (int mi = 0; mi < 4; ++mi) {
                bf16x8 av = ldsr(bufB, mi * 16 + lr, eb + k4 * 64 + lg * 16);
                a2[mi][0] = __builtin_amdgcn_mfma_f32_16x16x32_bf16(
                    av, bv0, a2[mi][0], 0, 0, 0);
                a2[mi][1] = __builtin_amdgcn_mfma_f32_16x16x32_bf16(
                    av, bv1, a2[mi][1], 0, 0, 0);
            }
        }
        // tanh -> XC into bufA (xl LDS copy dead after ph1; all past B_XV)
        #pragma unroll
        for (int mi = 0; mi < 4; ++mi)
            #pragma unroll
            for (int ni = 0; ni < 2; ++ni)
                #pragma unroll
                for (int j = 0; j < 4; ++j)
                    ldsw2(bufA, mi * 16 + lg * 4 + j,
                          (wn * 32 + ni * 16 + lr) * 2,
                          (bf16_t)tanh_fast(a2[mi][ni][j]));
        barrier_lds();                               // B_XC: XC visible
    }

    // ---- ph3: xu = XC @ Ucat^T (K=512 concat) + residual epilogue ----
    {
        f32x4 a3[4][2] = {};
        const bf16_t* up = Uw;
        #pragma unroll 2
        for (int ks = 0; ks < 16; ++ks) {
            bf16x8 bv0 = *(const bf16x8*)(up);
            bf16x8 bv1 = *(const bf16x8*)(up + 512);
            up += 1024;
            #pragma unroll
            for (int mi = 0; mi < 4; ++mi) {
                bf16x8 av = ldsr(bufA, mi * 16 + lr, ks * 64 + lg * 16);
                a3[mi][0] = __builtin_amdgcn_mfma_f32_16x16x32_bf16(
                    av, bv0, a3[mi][0], 0, 0, 0);
                a3[mi][1] = __builtin_amdgcn_mfma_f32_16x16x32_bf16(
                    av, bv1, a3[mi][1], 0, 0, 0);
            }
        }

        // out = xl + x0 * (xu + E*bias)   (gate == 1); per-thread
        // read-then-write of the same element -> in-place safe.
        #pragma unroll
        for (int ni = 0; ni < 2; ++ni) {
            int col = wn * 32 + ni * 16 + lr;
            float b4v = 4.0f * bl[col];
            #pragma unroll
            for (int mi = 0; mi < 4; ++mi)
                #pragma unroll
                for (int j = 0; j < 4; ++j) {
                    size_t idx = (size_t)(m0 + mi * 16 + lg * 4 + j) * DIM + col;
                    xl_out[idx] = xl_in[idx] + x0[idx] * (a3[mi][ni][j] + b4v);
                }
        }
    }
}

// ---------------- host ----------------

extern "C" void kernel_launch(void* const* d_in, const int* in_sizes, int n_in,
                              void* d_out, int out_size, void* d_ws, size_t ws_size,
                              hipStream_t stream) {
    const float* x  = (const float*)d_in[0];   // (B, D)
    const float* Us = (const float*)d_in[1];   // (L, E, D, R)
    const float* Cs = (const float*)d_in[2];   // (L, E, R, R)
    const float* Vs = (const float*)d_in[3];   // (L, E, D, R)
    // d_in[4] = G: softmax over singleton axis == 1.0 -> unused
    const float* bb = (const float*)d_in[5];   // (L, D)
    float* out = (float*)d_out;

    bf16_t* Vp = (bf16_t*)d_ws;                // 786432 bf16
    bf16_t* Up = Vp + 786432;                  // 786432 bf16
    bf16_t* Cp = Up + 786432;                  // 196608 bf16

    prep_pack<<<864, 256, 0, stream>>>(Vs, Us, Cs, Vp, Up, Cp);

    for (int l = 0; l < NLAYER; ++l) {
        k_layer<<<BATCH / 64, 1024, 0, stream>>>(
            (l == 0) ? x : out,                // xl_in (f32 master)
            x,                                 // x0
            Vp + (size_t)l * 262144,
            Up + (size_t)l * 262144,
            Cp + (size_t)l * 65536,
            bb + (size_t)l * DIM,
            out);                              // xl_out (in-place l>=1)
    }
}